// Round 5
// baseline (13083.641 us; speedup 1.0000x reference)
//
#include <hip/hip_runtime.h>
#include <math.h>

#define TT 2048
#define NKEYS 50000
#define EE 128
#define HH 512
#define H3 1536
#define DH 256
#define VOCAB 1704
#define NLOC 100

#define GB 32      // GRU worker blocks
#define GC 16      // h-elements per GRU worker
#define GRID_GRU 256
#define GXC 64     // gx prefetch chunk (steps)

#define QT 32      // flash queries per block
#define KT 64      // flash key tile
#define NSPL 4     // flash N-splits
#define SLICE 12500
#define KSTR 260   // padded LDS stride (f32) for K tile

// ---- workspace layout (float offsets) ----
static constexpr size_t OFF_Y     = 0;
static constexpr size_t OFF_GX    = OFF_Y    + (size_t)TT*EE;
static constexpr size_t OFF_OUT   = OFF_GX   + (size_t)TT*H3;
static constexpr size_t OFF_HBUF  = OFF_OUT  + (size_t)TT*HH;        // 2*HH uint64 = 4*HH floats
static constexpr size_t OFF_CLAIM = OFF_HBUF + 4*HH;                 // 2 ints (pad 8 floats)
static constexpr size_t OFF_MG    = OFF_CLAIM + 8;
static constexpr size_t OFF_ML    = OFF_MG   + (size_t)TT*DH;
static constexpr size_t OFF_C     = OFF_ML   + (size_t)TT*DH;
static constexpr size_t OFF_CG    = OFF_C    + (size_t)TT*DH;
static constexpr size_t OFF_BETA  = OFF_CG   + (size_t)TT*DH;
static constexpr size_t OFF_PGEN  = OFF_BETA + (size_t)TT*NLOC;
static constexpr size_t OFF_OP    = OFF_PGEN + TT;
static constexpr size_t OFF_MP    = OFF_OP   + (size_t)NSPL*TT*DH;
static constexpr size_t OFF_LP    = OFF_MP   + (size_t)NSPL*TT;

// ---------------- embedding + gx = y@W_ih^T + b_ih ----------------
__global__ void k_embed_gx(const int* __restrict__ X, const float* __restrict__ emb,
                           const float* __restrict__ W_ih, const float* __restrict__ b_ih,
                           float* __restrict__ Y, float* __restrict__ GX){
  int t = blockIdx.x, tid = threadIdx.x;
  __shared__ float yr[EE];
  int xid = X[t];
  if (tid < EE){ float v = emb[(size_t)xid*EE + tid]; yr[tid] = v; Y[(size_t)t*EE + tid] = v; }
  __syncthreads();
  for (int i=0;i<6;i++){
    int r = tid + 256*i;
    const float4* w = (const float4*)(W_ih + (size_t)r*EE);
    float acc = b_ih[r];
    #pragma unroll
    for (int k4=0;k4<EE/4;k4++){
      float4 wv = w[k4];
      acc += wv.x*yr[k4*4] + wv.y*yr[k4*4+1] + wv.z*yr[k4*4+2] + wv.w*yr[k4*4+3];
    }
    GX[(size_t)t*H3 + r] = acc;
  }
}

// ---------------- GRU scan: XCD-pinned workers, HBM off the per-step path ----------------
// Per-step path is now LDS/L2 only: gx staged in 64-step LDS chunks, out rows
// buffered in LDS and flushed per chunk (HBM store-ack no longer sits under the
// poll's vmcnt(0)). Exchange: packed (seq<<32|h) u64, relaxed agent atomics,
// parity double-buffer, 2 polled words/thread with s_sleep backoff.
__global__ __launch_bounds__(256) void k_gru(const float* __restrict__ GX, const float* __restrict__ W_hh,
          const float* __restrict__ b_hh, const float* __restrict__ glo, const float* __restrict__ loch,
          float* __restrict__ out, unsigned long long* hbuf, int* claim, int nblocks){
  __shared__ float wl[48*512];
  __shared__ float gxl[GXC*48];     // 12 KB: 64 steps x {r16,z16,n16}
  __shared__ float outbuf[GXC*GC];  // 4 KB: 64 steps x 16 h-elements
  __shared__ float hl[512];
  __shared__ float gh[48];
  __shared__ int widx_sh;
  int tid = threadIdx.x;

  if (tid==0){
    unsigned xcc;
    asm volatile("s_getreg_b32 %0, hwreg(HW_REG_XCC_ID, 0, 32)" : "=s"(xcc));
    int my = -1;
    if (xcc == 0u) my = atomicAdd(&claim[0], 1);
    __hip_atomic_fetch_add(&claim[1], 1, __ATOMIC_RELAXED, __HIP_MEMORY_SCOPE_AGENT);
    if (my < 0){
      for(;;){
        int c = __hip_atomic_load(&claim[0], __ATOMIC_RELAXED, __HIP_MEMORY_SCOPE_AGENT);
        if (c >= GB) break;
        int a = __hip_atomic_load(&claim[1], __ATOMIC_RELAXED, __HIP_MEMORY_SCOPE_AGENT);
        if (a >= nblocks){ my = atomicAdd(&claim[0], 1); break; }
      }
    }
    widx_sh = my;
  }
  __syncthreads();
  int b = widx_sh;
  if (b < 0 || b >= GB) return;

  int i0 = b*GC;
  for (int idx = tid; idx < 48*128; idx += 256){
    int r = idx >> 7, c4 = idx & 127;
    int grow = (r<16) ? (i0 + r) : (r<32) ? (512 + i0 + (r-16)) : (1024 + i0 + (r-32));
    ((float4*)wl)[idx] = ((const float4*)W_hh)[(size_t)grow*128 + c4];
  }
  hl[tid]     = glo[tid];
  hl[tid+256] = loch[tid];
  float bhr=0.f,bhz=0.f,bhn=0.f;
  if (tid < GC){ bhr = b_hh[i0+tid]; bhz = b_hh[512+i0+tid]; bhn = b_hh[1024+i0+tid]; }
  __syncthreads();
  int wave = tid>>6, lane = tid&63;
  for (int t=0;t<TT;t++){
    int s = t & (GXC-1);
    if (s == 0){
      // flush previous 64 out-rows (reads of outbuf ordered before this step's
      // gate writes by the post-poll barrier of step t-1 / the matvec barrier below)
      if (t > 0){
        int t0 = t - GXC;
        float4 ov = ((float4*)outbuf)[tid];
        int s2 = tid >> 2, c4 = tid & 3;
        *(float4*)&out[(size_t)(t0+s2)*HH + i0 + c4*4] = ov;
      }
      // stage next 64 steps of gx: 768 float4
      #pragma unroll
      for (int k=0;k<3;k++){
        int idx = tid + 256*k;           // 0..767
        int sp = idx / 12, q = idx % 12; // q: gate g=q>>2, sub c4=q&3
        int g = q >> 2, c4 = q & 3;
        ((float4*)gxl)[idx] = ((const float4*)(GX + (size_t)(t+sp)*H3 + g*512 + i0))[c4];
      }
    }
    float hprev=0.f;
    if (tid < GC) hprev = hl[i0+tid];
    float hreg[8];
    #pragma unroll
    for (int m=0;m<8;m++) hreg[m] = hl[lane + 64*m];
    #pragma unroll
    for (int rr=0; rr<12; rr++){
      int row = wave*12 + rr;
      const float* wr = &wl[row*512];
      float sacc = 0.f;
      #pragma unroll
      for (int m=0;m<8;m++) sacc = fmaf(wr[lane+64*m], hreg[m], sacc);
      #pragma unroll
      for (int off=32; off>0; off>>=1) sacc += __shfl_xor(sacc, off, 64);
      if (lane==0) gh[row] = sacc;
    }
    __syncthreads();   // gh ready; gxl chunk visible; outbuf flush-reads done
    int slot = (t+1)&1;
    if (tid < GC){
      int i = tid;
      float gxr = gxl[s*48 + i];
      float gxz = gxl[s*48 + 16 + i];
      float gxn = gxl[s*48 + 32 + i];
      float rg = 1.f/(1.f + __expf(-(gxr + gh[i]    + bhr)));
      float zg = 1.f/(1.f + __expf(-(gxz + gh[16+i] + bhz)));
      float nx = gxn + bhn + rg*gh[32+i];
      float ex = __expf(-2.f*fabsf(nx));
      float tt = (1.f-ex)/(1.f+ex);
      float ng = (nx >= 0.f) ? tt : -tt;
      float hn = (1.f - zg)*ng + zg*hprev;
      outbuf[s*GC + i] = hn;   // LDS buffer; flushed per chunk
      unsigned long long pk = ((unsigned long long)(unsigned)(t+1) << 32) | (unsigned long long)__float_as_uint(hn);
      __hip_atomic_store(&hbuf[slot*HH + i0 + i], pk, __ATOMIC_RELAXED, __HIP_MEMORY_SCOPE_AGENT);
    }
    if (t+1 < TT){
      unsigned int want = (unsigned)(t+1);
      const unsigned long long* hb = &hbuf[slot*HH];
      unsigned long long v0=0ull, v1=0ull;
      bool r0=false, r1=false;
      for(;;){
        if (!r0){ v0 = __hip_atomic_load(&hb[tid],     __ATOMIC_RELAXED, __HIP_MEMORY_SCOPE_AGENT); r0 = ((unsigned)(v0>>32) == want); }
        if (!r1){ v1 = __hip_atomic_load(&hb[tid+256], __ATOMIC_RELAXED, __HIP_MEMORY_SCOPE_AGENT); r1 = ((unsigned)(v1>>32) == want); }
        if (r0 && r1) break;
        __builtin_amdgcn_s_sleep(1);
      }
      hl[tid]     = __uint_as_float((unsigned)v0);
      hl[tid+256] = __uint_as_float((unsigned)v1);
      __syncthreads();  // hl of step t+1 ready
    }
  }
  // final flush of last 64 out-rows (order wave0's last gate writes first)
  __syncthreads();
  {
    int t0 = TT - GXC;
    float4 ov = ((float4*)outbuf)[tid];
    int s2 = tid >> 2, c4 = tid & 3;
    *(float4*)&out[(size_t)(t0+s2)*HH + i0 + c4*4] = ov;
  }
}

// ---------------- M_g = out@W_ga_g, M_l = out@W_ga_l, pgen base ----------------
__global__ void k_proj(const float* __restrict__ out, const float* __restrict__ Y,
                       const float* __restrict__ Wg, const float* __restrict__ Wl,
                       const float* __restrict__ wh, const float* __restrict__ wy,
                       float* __restrict__ MG, float* __restrict__ ML, float* __restrict__ PGB){
  int t = blockIdx.x, tid = threadIdx.x;
  __shared__ float orow[512];
  __shared__ float red[256];
  orow[tid]     = out[(size_t)t*HH + tid];
  orow[tid+256] = out[(size_t)t*HH + tid+256];
  __syncthreads();
  float mg=0.f, ml=0.f;
  for (int h=0; h<HH; h++){
    float ov = orow[h];
    mg = fmaf(ov, Wg[(size_t)h*DH + tid], mg);
    ml = fmaf(ov, Wl[(size_t)h*DH + tid], ml);
  }
  MG[(size_t)t*DH + tid] = mg;
  ML[(size_t)t*DH + tid] = ml;
  float pr = orow[tid]*wh[tid] + orow[tid+256]*wh[tid+256];
  if (tid < EE) pr += Y[(size_t)t*EE + tid]*wy[tid];
  red[tid] = pr;
  __syncthreads();
  for (int s=128; s>0; s>>=1){ if (tid < s) red[tid] += red[tid+s]; __syncthreads(); }
  if (tid==0) PGB[t] = red[0];
}

// ---------------- local attention + p_gen ----------------
__global__ void k_local(const float* __restrict__ ML, const float* __restrict__ locout,
                        const float* __restrict__ wc, const float* __restrict__ PGB,
                        float* __restrict__ C, float* __restrict__ BETA, float* __restrict__ PGEN){
  int t = blockIdx.x, tid = threadIdx.x; // 128 threads
  __shared__ float mlr[DH];
  __shared__ float sl[NLOC];
  __shared__ float crow[DH];
  __shared__ float red[128];
  __shared__ float mx; __shared__ float inv;
  mlr[tid]     = ML[(size_t)t*DH + tid];
  mlr[tid+128] = ML[(size_t)t*DH + tid+128];
  __syncthreads();
  if (tid < NLOC){
    const float* gl = locout + (size_t)tid*8*DH;
    float s=0.f;
    for (int e=0;e<DH;e++) s = fmaf(gl[e], mlr[e], s);
    sl[tid] = s;
  }
  __syncthreads();
  if (tid==0){ float m = sl[0]; for (int j=1;j<NLOC;j++) m = fmaxf(m, sl[j]); mx = m; }
  __syncthreads();
  if (tid < NLOC) sl[tid] = __expf(sl[tid]-mx);
  __syncthreads();
  if (tid==0){ float su=0.f; for (int j=0;j<NLOC;j++) su += sl[j]; inv = 1.f/su; }
  __syncthreads();
  if (tid < NLOC){ sl[tid] *= inv; BETA[(size_t)t*NLOC + tid] = sl[tid]; }
  __syncthreads();
  {
    float c0=0.f, c1=0.f;
    for (int j=0;j<NLOC;j++){
      float ga = sl[j];
      c0 = fmaf(ga, locout[(size_t)j*8*DH + tid],     c0);
      c1 = fmaf(ga, locout[(size_t)j*8*DH + tid+128], c1);
    }
    C[(size_t)t*DH + tid]     = c0;
    C[(size_t)t*DH + tid+128] = c1;
    crow[tid] = c0; crow[tid+128] = c1;
  }
  __syncthreads();
  red[tid] = crow[tid]*wc[tid] + crow[tid+128]*wc[tid+128];
  __syncthreads();
  for (int s=64;s>0;s>>=1){ if (tid<s) red[tid]+=red[tid+s]; __syncthreads(); }
  if (tid==0){
    float x = PGB[t] + red[0];
    PGEN[t] = (x > 0.f) ? x : 0.2f*x;
  }
}

// ---------------- global flash attention (f32), 4-way N split ----------------
__global__ __launch_bounds__(256) void k_flash(const float* __restrict__ MG, const float* __restrict__ G,
        float* __restrict__ OP, float* __restrict__ MP, float* __restrict__ LP){
  __shared__ float Mt[QT*DH];
  __shared__ float Kt[KT*KSTR];
  __shared__ float Pt[QT*(KT+2)];
  __shared__ float m_st[QT]; __shared__ float l_st[QT]; __shared__ float al_sh[QT];
  int bid = blockIdx.x;
  int qb = bid & 63, sl = bid >> 6;
  int q0 = qb*QT;
  int tid = threadIdx.x;
  for (int idx=tid; idx<QT*DH/4; idx+=256)
    ((float4*)Mt)[idx] = ((const float4*)(MG + (size_t)q0*DH))[idx];
  if (tid < QT){ m_st[tid] = -1e30f; l_st[tid] = 0.f; }
  int qg = tid >> 5, kg = tid & 31;
  float o[4][8];
  #pragma unroll
  for (int a=0;a<4;a++){
    #pragma unroll
    for (int b2=0;b2<8;b2++) o[a][b2]=0.f;
  }
  int k0base = sl*SLICE;
  __syncthreads();
  for (int k0=0; k0<SLICE; k0+=KT){
    int kt = (SLICE-k0) < KT ? (SLICE-k0) : KT;
    for (int idx=tid; idx<KT*(DH/4); idx+=256){
      int r = idx/(DH/4), c = idx%(DH/4);
      if (r < kt)
        *(float4*)&Kt[r*KSTR + c*4] = ((const float4*)(G + (size_t)(k0base+k0+r)*DH))[c];
    }
    __syncthreads();
    float s[4][2];
    #pragma unroll
    for (int a=0;a<4;a++){ s[a][0]=0.f; s[a][1]=0.f; }
    #pragma unroll 4
    for (int d4=0; d4<DH/4; d4++){
      float4 k0v = *(float4*)&Kt[(kg*2+0)*KSTR + d4*4];
      float4 k1v = *(float4*)&Kt[(kg*2+1)*KSTR + d4*4];
      #pragma unroll
      for (int qi=0;qi<4;qi++){
        float4 mv = *(float4*)&Mt[(qg*4+qi)*DH + d4*4];
        s[qi][0] += mv.x*k0v.x + mv.y*k0v.y + mv.z*k0v.z + mv.w*k0v.w;
        s[qi][1] += mv.x*k1v.x + mv.y*k1v.y + mv.z*k1v.z + mv.w*k1v.w;
      }
    }
    bool v0 = (kg*2+0) < kt, v1 = (kg*2+1) < kt;
    #pragma unroll
    for (int qi=0;qi<4;qi++){
      if (!v0) s[qi][0] = -1e30f;
      if (!v1) s[qi][1] = -1e30f;
      int q = qg*4+qi;
      float mloc = fmaxf(s[qi][0], s[qi][1]);
      #pragma unroll
      for (int msk=16; msk>0; msk>>=1) mloc = fmaxf(mloc, __shfl_xor(mloc, msk, 64));
      float mold = m_st[q];
      float mnew = fmaxf(mold, mloc);
      float p0 = v0 ? __expf(s[qi][0]-mnew) : 0.f;
      float p1 = v1 ? __expf(s[qi][1]-mnew) : 0.f;
      float lloc = p0+p1;
      #pragma unroll
      for (int msk=16; msk>0; msk>>=1) lloc += __shfl_xor(lloc, msk, 64);
      float al = __expf(mold - mnew);
      if (kg==0){ m_st[q]=mnew; l_st[q] = l_st[q]*al + lloc; al_sh[q]=al; }
      Pt[q*(KT+2) + kg*2+0] = p0;
      Pt[q*(KT+2) + kg*2+1] = p1;
    }
    __syncthreads();
    int dg = kg;
    #pragma unroll
    for (int qi=0;qi<4;qi++){
      float al = al_sh[qg*4+qi];
      #pragma unroll
      for (int j=0;j<8;j++) o[qi][j] *= al;
    }
    for (int k=0;k<kt;k++){
      float4 vv0 = *(float4*)&Kt[k*KSTR + dg*8];
      float4 vv1 = *(float4*)&Kt[k*KSTR + dg*8+4];
      #pragma unroll
      for (int qi=0;qi<4;qi++){
        float p = Pt[(qg*4+qi)*(KT+2) + k];
        o[qi][0] = fmaf(p, vv0.x, o[qi][0]);
        o[qi][1] = fmaf(p, vv0.y, o[qi][1]);
        o[qi][2] = fmaf(p, vv0.z, o[qi][2]);
        o[qi][3] = fmaf(p, vv0.w, o[qi][3]);
        o[qi][4] = fmaf(p, vv1.x, o[qi][4]);
        o[qi][5] = fmaf(p, vv1.y, o[qi][5]);
        o[qi][6] = fmaf(p, vv1.z, o[qi][6]);
        o[qi][7] = fmaf(p, vv1.w, o[qi][7]);
      }
    }
    __syncthreads();
  }
  #pragma unroll
  for (int qi=0;qi<4;qi++){
    int q = q0 + qg*4 + qi;
    size_t base = ((size_t)sl*TT + q)*DH + kg*8;
    float4 w0 = make_float4(o[qi][0],o[qi][1],o[qi][2],o[qi][3]);
    float4 w1 = make_float4(o[qi][4],o[qi][5],o[qi][6],o[qi][7]);
    *(float4*)&OP[base]   = w0;
    *(float4*)&OP[base+4] = w1;
  }
  if (tid < QT){ MP[(size_t)sl*TT + q0 + tid] = m_st[tid]; LP[(size_t)sl*TT + q0 + tid] = l_st[tid]; }
}

// ---------------- combine flash splits ----------------
__global__ void k_combine(const float* __restrict__ OP, const float* __restrict__ MP,
                          const float* __restrict__ LP, float* __restrict__ CG){
  int q = blockIdx.x, tid = threadIdx.x; // 64 threads
  float m0 = MP[q], m1 = MP[TT+q], m2 = MP[2*TT+q], m3 = MP[3*TT+q];
  float M = fmaxf(fmaxf(m0,m1), fmaxf(m2,m3));
  float w0 = __expf(m0-M), w1 = __expf(m1-M), w2 = __expf(m2-M), w3 = __expf(m3-M);
  float denom = LP[q]*w0 + LP[TT+q]*w1 + LP[2*TT+q]*w2 + LP[3*TT+q]*w3;
  float inv = 1.f/denom;
  for (int d = tid; d < DH; d += 64){
    float v = OP[((size_t)0*TT+q)*DH+d]*w0 + OP[((size_t)1*TT+q)*DH+d]*w1
            + OP[((size_t)2*TT+q)*DH+d]*w2 + OP[((size_t)3*TT+q)*DH+d]*w3;
    CG[(size_t)q*DH + d] = v*inv;
  }
}

// ---------------- P_vocab softmax, mixture, final projection ----------------
__global__ void k_final(const float* __restrict__ out, const float* __restrict__ C,
        const float* __restrict__ CG, const float* __restrict__ BETA, const float* __restrict__ PGEN,
        const float* __restrict__ Wv_w, const float* __restrict__ Wv_b,
        const float* __restrict__ fc_w, const float* __restrict__ fc_b, float* __restrict__ O){
  int t = blockIdx.x, tid = threadIdx.x;
  __shared__ float cat[1024];
  __shared__ float pw[NLOC];
  __shared__ float mx; __shared__ float inv;
  cat[tid]     = out[(size_t)t*HH + tid];
  cat[tid+256] = out[(size_t)t*HH + tid+256];
  cat[512+tid] = C[(size_t)t*DH + tid];
  cat[768+tid] = CG[(size_t)t*DH + tid];
  __syncthreads();
  if (tid < NLOC){
    const float4* w = (const float4*)(Wv_w + (size_t)tid*1024);
    float acc = Wv_b[tid];
    for (int i4=0;i4<256;i4++){
      float4 wv = w[i4];
      acc += wv.x*cat[i4*4] + wv.y*cat[i4*4+1] + wv.z*cat[i4*4+2] + wv.w*cat[i4*4+3];
    }
    pw[tid] = acc;
  }
  __syncthreads();
  if (tid==0){ float m=pw[0]; for (int j=1;j<NLOC;j++) m=fmaxf(m,pw[j]); mx=m; }
  __syncthreads();
  if (tid<NLOC) pw[tid] = __expf(pw[tid]-mx);
  __syncthreads();
  if (tid==0){ float s=0.f; for(int j=0;j<NLOC;j++) s+=pw[j]; inv=1.f/s; }
  __syncthreads();
  float pg = PGEN[t];
  if (tid<NLOC) pw[tid] = pg*pw[tid]*inv + (1.f-pg)*BETA[(size_t)t*NLOC+tid];
  __syncthreads();
  for (int o_=tid; o_<VOCAB; o_+=256){
    const float4* fw = (const float4*)(fc_w + (size_t)o_*NLOC);
    float acc = fc_b[o_];
    #pragma unroll
    for (int p4=0;p4<25;p4++){
      float4 wv = fw[p4];
      acc += wv.x*pw[p4*4] + wv.y*pw[p4*4+1] + wv.z*pw[p4*4+2] + wv.w*pw[p4*4+3];
    }
    O[(size_t)t*VOCAB + o_] = acc;
  }
}

extern "C" void kernel_launch(void* const* d_in, const int* in_sizes, int n_in,
                              void* d_out, int out_size, void* d_ws, size_t ws_size,
                              hipStream_t stream) {
  (void)in_sizes; (void)n_in; (void)out_size; (void)ws_size;
  const int*   X    = (const int*)d_in[0];
  const float* glo  = (const float*)d_in[1];
  const float* loch = (const float*)d_in[2];
  const float* loco = (const float*)d_in[3];
  const float* emb  = (const float*)d_in[4];
  const float* W_ih = (const float*)d_in[5];
  const float* W_hh = (const float*)d_in[6];
  const float* b_ih = (const float*)d_in[7];
  const float* b_hh = (const float*)d_in[8];
  const float* Wg   = (const float*)d_in[9];
  const float* Wl   = (const float*)d_in[10];
  const float* Wv_w = (const float*)d_in[11];
  const float* Wv_b = (const float*)d_in[12];
  const float* wh   = (const float*)d_in[13];
  const float* wc   = (const float*)d_in[14];
  const float* wy   = (const float*)d_in[15];
  const float* fc_w = (const float*)d_in[16];
  const float* fc_b = (const float*)d_in[17];

  float* ws   = (float*)d_ws;
  float* Y    = ws + OFF_Y;
  float* GX   = ws + OFF_GX;
  float* OUT  = ws + OFF_OUT;
  unsigned long long* HBUF = (unsigned long long*)(ws + OFF_HBUF);
  int*   CLAIM = (int*)(ws + OFF_CLAIM);
  float* MG   = ws + OFF_MG;
  float* ML   = ws + OFF_ML;
  float* C    = ws + OFF_C;
  float* CG   = ws + OFF_CG;
  float* BETA = ws + OFF_BETA;
  float* PGEN = ws + OFF_PGEN;
  float* OP   = ws + OFF_OP;
  float* MP   = ws + OFF_MP;
  float* LP   = ws + OFF_LP;

  hipMemsetAsync(HBUF, 0, 2*HH*sizeof(unsigned long long), stream);
  hipMemsetAsync(CLAIM, 0, 2*sizeof(int), stream);
  k_embed_gx<<<TT, 256, 0, stream>>>(X, emb, W_ih, b_ih, Y, GX);
  k_gru<<<GRID_GRU, 256, 0, stream>>>(GX, W_hh, b_hh, glo, loch, OUT, HBUF, CLAIM, GRID_GRU);
  k_proj<<<TT, 256, 0, stream>>>(OUT, Y, Wg, Wl, wh, wy, MG, ML, PGEN);
  k_local<<<TT, 128, 0, stream>>>(ML, loco, wc, PGEN, C, BETA, PGEN);
  k_flash<<<QT*NSPL*2, 256, 0, stream>>>(MG, glo, OP, MP, LP);
  k_combine<<<TT, 64, 0, stream>>>(OP, MP, LP, CG);
  k_final<<<TT, 256, 0, stream>>>(OUT, C, CG, BETA, PGEN, Wv_w, Wv_b, fc_w, fc_b, (float*)d_out);
}

// Round 6
// 9845.716 us; speedup vs baseline: 1.3289x; 1.3289x over previous
//
#include <hip/hip_runtime.h>
#include <math.h>

#define TT 2048
#define NKEYS 50000
#define EE 128
#define HH 512
#define H3 1536
#define DH 256
#define VOCAB 1704
#define NLOC 100

#define GB 32      // GRU worker blocks
#define GC 16      // h-elements per GRU worker
#define GRID_GRU 256
#define GXC 64     // gx prefetch chunk (steps)

#define QT 32      // flash queries per block
#define KT 64      // flash key tile
#define NSPL 4     // flash N-splits
#define SLICE 12500
#define KSTR 260   // padded LDS stride (f32) for K tile

// ---- workspace layout (float offsets) ----
static constexpr size_t OFF_Y     = 0;
static constexpr size_t OFF_GX    = OFF_Y    + (size_t)TT*EE;
static constexpr size_t OFF_OUT   = OFF_GX   + (size_t)TT*H3;
static constexpr size_t OFF_HBUF  = OFF_OUT  + (size_t)TT*HH;        // 2*HH uint64 = 4*HH floats
static constexpr size_t OFF_CLAIM = OFF_HBUF + 4*HH;                 // 2 ints (pad 8 floats)
static constexpr size_t OFF_MG    = OFF_CLAIM + 8;
static constexpr size_t OFF_ML    = OFF_MG   + (size_t)TT*DH;
static constexpr size_t OFF_C     = OFF_ML   + (size_t)TT*DH;
static constexpr size_t OFF_CG    = OFF_C    + (size_t)TT*DH;
static constexpr size_t OFF_BETA  = OFF_CG   + (size_t)TT*DH;
static constexpr size_t OFF_PGEN  = OFF_BETA + (size_t)TT*NLOC;
static constexpr size_t OFF_OP    = OFF_PGEN + TT;
static constexpr size_t OFF_MP    = OFF_OP   + (size_t)NSPL*TT*DH;
static constexpr size_t OFF_LP    = OFF_MP   + (size_t)NSPL*TT;

// ---------------- embedding + gx = y@W_ih^T + b_ih ----------------
__global__ void k_embed_gx(const int* __restrict__ X, const float* __restrict__ emb,
                           const float* __restrict__ W_ih, const float* __restrict__ b_ih,
                           float* __restrict__ Y, float* __restrict__ GX){
  int t = blockIdx.x, tid = threadIdx.x;
  __shared__ float yr[EE];
  int xid = X[t];
  if (tid < EE){ float v = emb[(size_t)xid*EE + tid]; yr[tid] = v; Y[(size_t)t*EE + tid] = v; }
  __syncthreads();
  for (int i=0;i<6;i++){
    int r = tid + 256*i;
    const float4* w = (const float4*)(W_ih + (size_t)r*EE);
    float acc = b_ih[r];
    #pragma unroll
    for (int k4=0;k4<EE/4;k4++){
      float4 wv = w[k4];
      acc += wv.x*yr[k4*4] + wv.y*yr[k4*4+1] + wv.z*yr[k4*4+2] + wv.w*yr[k4*4+3];
    }
    GX[(size_t)t*H3 + r] = acc;
  }
}

// ---------------- GRU scan: register-resident W_hh, wave-local gates, 1 barrier/step ----------------
// Wave w owns rows {c*16 + 4w + j : c in 0..2 (r,z,n), j in 0..3}. Each thread
// holds its 12x8 weight fragment in VGPRs (cols lane+64m). Reduce: 12 partials
// -> LDS transpose (same-wave, no barrier) -> 4-lane sum + 2 shfl_xor. Each
// wave gates+stores its own 4 h-elements immediately (no cross-wave barrier).
// One __syncthreads per step (hl ready). hl overwrite is ordered by the data
// dependency: poll success needs own block's wave-3 store, which follows
// wave-3's hl reads.
__global__ __launch_bounds__(256, 1) void k_gru(const float* __restrict__ GX, const float* __restrict__ W_hh,
          const float* __restrict__ b_hh, const float* __restrict__ glo, const float* __restrict__ loch,
          float* __restrict__ out, unsigned long long* hbuf, int* claim, int nblocks){
  __shared__ float gxl[GXC*48];     // 12 KB
  __shared__ float outbuf[GXC*GC];  // 4 KB
  __shared__ float hl[512];         // 2 KB
  __shared__ float ghw[4][12];
  __shared__ float pbuf[4][12][65]; // 12.5 KB, stride-65: reduce reads max 2-way (free)
  __shared__ int widx_sh;
  int tid = threadIdx.x;

  if (tid==0){
    unsigned xcc;
    asm volatile("s_getreg_b32 %0, hwreg(HW_REG_XCC_ID, 0, 32)" : "=s"(xcc));
    int my = -1;
    if (xcc == 0u) my = atomicAdd(&claim[0], 1);
    __hip_atomic_fetch_add(&claim[1], 1, __ATOMIC_RELAXED, __HIP_MEMORY_SCOPE_AGENT);
    if (my < 0){
      for(;;){
        int c = __hip_atomic_load(&claim[0], __ATOMIC_RELAXED, __HIP_MEMORY_SCOPE_AGENT);
        if (c >= GB) break;
        int a = __hip_atomic_load(&claim[1], __ATOMIC_RELAXED, __HIP_MEMORY_SCOPE_AGENT);
        if (a >= nblocks){ my = atomicAdd(&claim[0], 1); break; }
      }
    }
    widx_sh = my;
  }
  __syncthreads();
  int b = widx_sh;
  if (b < 0 || b >= GB) return;

  int i0 = b*GC;
  int wave = tid>>6, lane = tid&63;

  // weights into VGPRs (coalesced per-instruction: lanes read consecutive cols)
  float wreg[12][8];
  #pragma unroll
  for (int c=0;c<3;c++){
    #pragma unroll
    for (int j=0;j<4;j++){
      const float* wr = W_hh + (size_t)(c*512 + i0 + 4*wave + j)*512;
      #pragma unroll
      for (int m=0;m<8;m++) wreg[c*4+j][m] = wr[lane + 64*m];
    }
  }
  hl[tid]     = glo[tid];
  hl[tid+256] = loch[tid];
  float bhr=0.f,bhz=0.f,bhn=0.f,hprev=0.f;
  int e = 4*wave + lane;   // gate element (valid when lane<4)
  if (lane < 4){
    bhr = b_hh[i0+e]; bhz = b_hh[512+i0+e]; bhn = b_hh[1024+i0+e];
    int hi = i0 + e;
    hprev = (hi < 256) ? glo[hi] : loch[hi-256];
  }
  __syncthreads();
  int r4 = lane>>2, q4 = lane&3;
  for (int t=0;t<TT;t++){
    int s = t & (GXC-1);
    if (s == 0){
      if (t > 0){
        int t0 = t - GXC;
        float4 ov = ((float4*)outbuf)[tid];
        int s2 = tid >> 2, c4 = tid & 3;
        *(float4*)&out[(size_t)(t0+s2)*HH + i0 + c4*4] = ov;
      }
      #pragma unroll
      for (int k=0;k<3;k++){
        int idx = tid + 256*k;
        int sp = idx / 12, q = idx % 12;
        int g = q >> 2, c4 = q & 3;
        ((float4*)gxl)[idx] = ((const float4*)(GX + (size_t)(t+sp)*H3 + g*512 + i0))[c4];
      }
      __syncthreads();  // gxl staged before this chunk's gates read it
    }
    float hreg[8];
    #pragma unroll
    for (int m=0;m<8;m++) hreg[m] = hl[lane + 64*m];
    float p[12];
    #pragma unroll
    for (int rr=0;rr<12;rr++){
      float acc = 0.f;
      #pragma unroll
      for (int m=0;m<8;m++) acc = fmaf(wreg[rr][m], hreg[m], acc);
      p[rr] = acc;
    }
    #pragma unroll
    for (int rr=0;rr<12;rr++) pbuf[wave][rr][lane] = p[rr];
    __builtin_amdgcn_wave_barrier();
    if (r4 < 12){
      const float* pb = &pbuf[wave][r4][q4*16];
      float sum = 0.f;
      #pragma unroll
      for (int j=0;j<16;j++) sum += pb[j];
      sum += __shfl_xor(sum, 1, 64);
      sum += __shfl_xor(sum, 2, 64);
      if (q4 == 0) ghw[wave][r4] = sum;
    }
    __builtin_amdgcn_wave_barrier();
    int slot = (t+1)&1;
    if (lane < 4){
      float ghr = ghw[wave][lane];
      float ghz = ghw[wave][4+lane];
      float ghn = ghw[wave][8+lane];
      float gxr = gxl[s*48 + e];
      float gxz = gxl[s*48 + 16 + e];
      float gxn = gxl[s*48 + 32 + e];
      float rg = 1.f/(1.f + __expf(-(gxr + ghr + bhr)));
      float zg = 1.f/(1.f + __expf(-(gxz + ghz + bhz)));
      float nx = gxn + bhn + rg*ghn;
      float ex = __expf(-2.f*fabsf(nx));
      float tt2 = (1.f-ex)/(1.f+ex);
      float ng = (nx >= 0.f) ? tt2 : -tt2;
      float hn = (1.f - zg)*ng + zg*hprev;
      outbuf[s*GC + e] = hn;
      unsigned long long pk = ((unsigned long long)(unsigned)(t+1) << 32) | (unsigned long long)__float_as_uint(hn);
      __hip_atomic_store(&hbuf[slot*HH + i0 + e], pk, __ATOMIC_RELAXED, __HIP_MEMORY_SCOPE_AGENT);
      hprev = hn;
    }
    if (t+1 < TT){
      unsigned want = (unsigned)(t+1);
      const unsigned long long* hb = &hbuf[slot*HH];
      unsigned long long v0=0ull, v1=0ull;
      bool f0=false, f1=false;
      for(;;){
        if (!f0){ v0 = __hip_atomic_load(&hb[tid],     __ATOMIC_RELAXED, __HIP_MEMORY_SCOPE_AGENT); f0 = ((unsigned)(v0>>32) == want); }
        if (!f1){ v1 = __hip_atomic_load(&hb[tid+256], __ATOMIC_RELAXED, __HIP_MEMORY_SCOPE_AGENT); f1 = ((unsigned)(v1>>32) == want); }
        if (f0 && f1) break;
        __builtin_amdgcn_s_sleep(1);
      }
      hl[tid]     = __uint_as_float((unsigned)v0);
      hl[tid+256] = __uint_as_float((unsigned)v1);
      __syncthreads();  // hl of step t+1 ready
    }
  }
  __syncthreads();
  {
    int t0 = TT - GXC;
    float4 ov = ((float4*)outbuf)[tid];
    int s2 = tid >> 2, c4 = tid & 3;
    *(float4*)&out[(size_t)(t0+s2)*HH + i0 + c4*4] = ov;
  }
}

// ---------------- M_g = out@W_ga_g, M_l = out@W_ga_l, pgen base ----------------
__global__ void k_proj(const float* __restrict__ out, const float* __restrict__ Y,
                       const float* __restrict__ Wg, const float* __restrict__ Wl,
                       const float* __restrict__ wh, const float* __restrict__ wy,
                       float* __restrict__ MG, float* __restrict__ ML, float* __restrict__ PGB){
  int t = blockIdx.x, tid = threadIdx.x;
  __shared__ float orow[512];
  __shared__ float red[256];
  orow[tid]     = out[(size_t)t*HH + tid];
  orow[tid+256] = out[(size_t)t*HH + tid+256];
  __syncthreads();
  float mg=0.f, ml=0.f;
  for (int h=0; h<HH; h++){
    float ov = orow[h];
    mg = fmaf(ov, Wg[(size_t)h*DH + tid], mg);
    ml = fmaf(ov, Wl[(size_t)h*DH + tid], ml);
  }
  MG[(size_t)t*DH + tid] = mg;
  ML[(size_t)t*DH + tid] = ml;
  float pr = orow[tid]*wh[tid] + orow[tid+256]*wh[tid+256];
  if (tid < EE) pr += Y[(size_t)t*EE + tid]*wy[tid];
  red[tid] = pr;
  __syncthreads();
  for (int s=128; s>0; s>>=1){ if (tid < s) red[tid] += red[tid+s]; __syncthreads(); }
  if (tid==0) PGB[t] = red[0];
}

// ---------------- local attention + p_gen ----------------
__global__ void k_local(const float* __restrict__ ML, const float* __restrict__ locout,
                        const float* __restrict__ wc, const float* __restrict__ PGB,
                        float* __restrict__ C, float* __restrict__ BETA, float* __restrict__ PGEN){
  int t = blockIdx.x, tid = threadIdx.x; // 128 threads
  __shared__ float mlr[DH];
  __shared__ float sl[NLOC];
  __shared__ float crow[DH];
  __shared__ float red[128];
  __shared__ float mx; __shared__ float inv;
  mlr[tid]     = ML[(size_t)t*DH + tid];
  mlr[tid+128] = ML[(size_t)t*DH + tid+128];
  __syncthreads();
  if (tid < NLOC){
    const float* gl = locout + (size_t)tid*8*DH;
    float s=0.f;
    for (int e=0;e<DH;e++) s = fmaf(gl[e], mlr[e], s);
    sl[tid] = s;
  }
  __syncthreads();
  if (tid==0){ float m = sl[0]; for (int j=1;j<NLOC;j++) m = fmaxf(m, sl[j]); mx = m; }
  __syncthreads();
  if (tid < NLOC) sl[tid] = __expf(sl[tid]-mx);
  __syncthreads();
  if (tid==0){ float su=0.f; for (int j=0;j<NLOC;j++) su += sl[j]; inv = 1.f/su; }
  __syncthreads();
  if (tid < NLOC){ sl[tid] *= inv; BETA[(size_t)t*NLOC + tid] = sl[tid]; }
  __syncthreads();
  {
    float c0=0.f, c1=0.f;
    for (int j=0;j<NLOC;j++){
      float ga = sl[j];
      c0 = fmaf(ga, locout[(size_t)j*8*DH + tid],     c0);
      c1 = fmaf(ga, locout[(size_t)j*8*DH + tid+128], c1);
    }
    C[(size_t)t*DH + tid]     = c0;
    C[(size_t)t*DH + tid+128] = c1;
    crow[tid] = c0; crow[tid+128] = c1;
  }
  __syncthreads();
  red[tid] = crow[tid]*wc[tid] + crow[tid+128]*wc[tid+128];
  __syncthreads();
  for (int s=64;s>0;s>>=1){ if (tid<s) red[tid]+=red[tid+s]; __syncthreads(); }
  if (tid==0){
    float x = PGB[t] + red[0];
    PGEN[t] = (x > 0.f) ? x : 0.2f*x;
  }
}

// ---------------- global flash attention (f32), 4-way N split ----------------
__global__ __launch_bounds__(256) void k_flash(const float* __restrict__ MG, const float* __restrict__ G,
        float* __restrict__ OP, float* __restrict__ MP, float* __restrict__ LP){
  __shared__ float Mt[QT*DH];
  __shared__ float Kt[KT*KSTR];
  __shared__ float Pt[QT*(KT+2)];
  __shared__ float m_st[QT]; __shared__ float l_st[QT]; __shared__ float al_sh[QT];
  int bid = blockIdx.x;
  int qb = bid & 63, sl = bid >> 6;
  int q0 = qb*QT;
  int tid = threadIdx.x;
  for (int idx=tid; idx<QT*DH/4; idx+=256)
    ((float4*)Mt)[idx] = ((const float4*)(MG + (size_t)q0*DH))[idx];
  if (tid < QT){ m_st[tid] = -1e30f; l_st[tid] = 0.f; }
  int qg = tid >> 5, kg = tid & 31;
  float o[4][8];
  #pragma unroll
  for (int a=0;a<4;a++){
    #pragma unroll
    for (int b2=0;b2<8;b2++) o[a][b2]=0.f;
  }
  int k0base = sl*SLICE;
  __syncthreads();
  for (int k0=0; k0<SLICE; k0+=KT){
    int kt = (SLICE-k0) < KT ? (SLICE-k0) : KT;
    for (int idx=tid; idx<KT*(DH/4); idx+=256){
      int r = idx/(DH/4), c = idx%(DH/4);
      if (r < kt)
        *(float4*)&Kt[r*KSTR + c*4] = ((const float4*)(G + (size_t)(k0base+k0+r)*DH))[c];
    }
    __syncthreads();
    float s[4][2];
    #pragma unroll
    for (int a=0;a<4;a++){ s[a][0]=0.f; s[a][1]=0.f; }
    #pragma unroll 4
    for (int d4=0; d4<DH/4; d4++){
      float4 k0v = *(float4*)&Kt[(kg*2+0)*KSTR + d4*4];
      float4 k1v = *(float4*)&Kt[(kg*2+1)*KSTR + d4*4];
      #pragma unroll
      for (int qi=0;qi<4;qi++){
        float4 mv = *(float4*)&Mt[(qg*4+qi)*DH + d4*4];
        s[qi][0] += mv.x*k0v.x + mv.y*k0v.y + mv.z*k0v.z + mv.w*k0v.w;
        s[qi][1] += mv.x*k1v.x + mv.y*k1v.y + mv.z*k1v.z + mv.w*k1v.w;
      }
    }
    bool v0 = (kg*2+0) < kt, v1 = (kg*2+1) < kt;
    #pragma unroll
    for (int qi=0;qi<4;qi++){
      if (!v0) s[qi][0] = -1e30f;
      if (!v1) s[qi][1] = -1e30f;
      int q = qg*4+qi;
      float mloc = fmaxf(s[qi][0], s[qi][1]);
      #pragma unroll
      for (int msk=16; msk>0; msk>>=1) mloc = fmaxf(mloc, __shfl_xor(mloc, msk, 64));
      float mold = m_st[q];
      float mnew = fmaxf(mold, mloc);
      float p0 = v0 ? __expf(s[qi][0]-mnew) : 0.f;
      float p1 = v1 ? __expf(s[qi][1]-mnew) : 0.f;
      float lloc = p0+p1;
      #pragma unroll
      for (int msk=16; msk>0; msk>>=1) lloc += __shfl_xor(lloc, msk, 64);
      float al = __expf(mold - mnew);
      if (kg==0){ m_st[q]=mnew; l_st[q] = l_st[q]*al + lloc; al_sh[q]=al; }
      Pt[q*(KT+2) + kg*2+0] = p0;
      Pt[q*(KT+2) + kg*2+1] = p1;
    }
    __syncthreads();
    int dg = kg;
    #pragma unroll
    for (int qi=0;qi<4;qi++){
      float al = al_sh[qg*4+qi];
      #pragma unroll
      for (int j=0;j<8;j++) o[qi][j] *= al;
    }
    for (int k=0;k<kt;k++){
      float4 vv0 = *(float4*)&Kt[k*KSTR + dg*8];
      float4 vv1 = *(float4*)&Kt[k*KSTR + dg*8+4];
      #pragma unroll
      for (int qi=0;qi<4;qi++){
        float p = Pt[(qg*4+qi)*(KT+2) + k];
        o[qi][0] = fmaf(p, vv0.x, o[qi][0]);
        o[qi][1] = fmaf(p, vv0.y, o[qi][1]);
        o[qi][2] = fmaf(p, vv0.z, o[qi][2]);
        o[qi][3] = fmaf(p, vv0.w, o[qi][3]);
        o[qi][4] = fmaf(p, vv1.x, o[qi][4]);
        o[qi][5] = fmaf(p, vv1.y, o[qi][5]);
        o[qi][6] = fmaf(p, vv1.z, o[qi][6]);
        o[qi][7] = fmaf(p, vv1.w, o[qi][7]);
      }
    }
    __syncthreads();
  }
  #pragma unroll
  for (int qi=0;qi<4;qi++){
    int q = q0 + qg*4 + qi;
    size_t base = ((size_t)sl*TT + q)*DH + kg*8;
    float4 w0 = make_float4(o[qi][0],o[qi][1],o[qi][2],o[qi][3]);
    float4 w1 = make_float4(o[qi][4],o[qi][5],o[qi][6],o[qi][7]);
    *(float4*)&OP[base]   = w0;
    *(float4*)&OP[base+4] = w1;
  }
  if (tid < QT){ MP[(size_t)sl*TT + q0 + tid] = m_st[tid]; LP[(size_t)sl*TT + q0 + tid] = l_st[tid]; }
}

// ---------------- combine flash splits ----------------
__global__ void k_combine(const float* __restrict__ OP, const float* __restrict__ MP,
                          const float* __restrict__ LP, float* __restrict__ CG){
  int q = blockIdx.x, tid = threadIdx.x; // 64 threads
  float m0 = MP[q], m1 = MP[TT+q], m2 = MP[2*TT+q], m3 = MP[3*TT+q];
  float M = fmaxf(fmaxf(m0,m1), fmaxf(m2,m3));
  float w0 = __expf(m0-M), w1 = __expf(m1-M), w2 = __expf(m2-M), w3 = __expf(m3-M);
  float denom = LP[q]*w0 + LP[TT+q]*w1 + LP[2*TT+q]*w2 + LP[3*TT+q]*w3;
  float inv = 1.f/denom;
  for (int d = tid; d < DH; d += 64){
    float v = OP[((size_t)0*TT+q)*DH+d]*w0 + OP[((size_t)1*TT+q)*DH+d]*w1
            + OP[((size_t)2*TT+q)*DH+d]*w2 + OP[((size_t)3*TT+q)*DH+d]*w3;
    CG[(size_t)q*DH + d] = v*inv;
  }
}

// ---------------- P_vocab softmax, mixture, final projection ----------------
__global__ void k_final(const float* __restrict__ out, const float* __restrict__ C,
        const float* __restrict__ CG, const float* __restrict__ BETA, const float* __restrict__ PGEN,
        const float* __restrict__ Wv_w, const float* __restrict__ Wv_b,
        const float* __restrict__ fc_w, const float* __restrict__ fc_b, float* __restrict__ O){
  int t = blockIdx.x, tid = threadIdx.x;
  __shared__ float cat[1024];
  __shared__ float pw[NLOC];
  __shared__ float mx; __shared__ float inv;
  cat[tid]     = out[(size_t)t*HH + tid];
  cat[tid+256] = out[(size_t)t*HH + tid+256];
  cat[512+tid] = C[(size_t)t*DH + tid];
  cat[768+tid] = CG[(size_t)t*DH + tid];
  __syncthreads();
  if (tid < NLOC){
    const float4* w = (const float4*)(Wv_w + (size_t)tid*1024);
    float acc = Wv_b[tid];
    for (int i4=0;i4<256;i4++){
      float4 wv = w[i4];
      acc += wv.x*cat[i4*4] + wv.y*cat[i4*4+1] + wv.z*cat[i4*4+2] + wv.w*cat[i4*4+3];
    }
    pw[tid] = acc;
  }
  __syncthreads();
  if (tid==0){ float m=pw[0]; for (int j=1;j<NLOC;j++) m=fmaxf(m,pw[j]); mx=m; }
  __syncthreads();
  if (tid<NLOC) pw[tid] = __expf(pw[tid]-mx);
  __syncthreads();
  if (tid==0){ float s=0.f; for(int j=0;j<NLOC;j++) s+=pw[j]; inv=1.f/s; }
  __syncthreads();
  float pg = PGEN[t];
  if (tid<NLOC) pw[tid] = pg*pw[tid]*inv + (1.f-pg)*BETA[(size_t)t*NLOC+tid];
  __syncthreads();
  for (int o_=tid; o_<VOCAB; o_+=256){
    const float4* fw = (const float4*)(fc_w + (size_t)o_*NLOC);
    float acc = fc_b[o_];
    #pragma unroll
    for (int p4=0;p4<25;p4++){
      float4 wv = fw[p4];
      acc += wv.x*pw[p4*4] + wv.y*pw[p4*4+1] + wv.z*pw[p4*4+2] + wv.w*pw[p4*4+3];
    }
    O[(size_t)t*VOCAB + o_] = acc;
  }
}

extern "C" void kernel_launch(void* const* d_in, const int* in_sizes, int n_in,
                              void* d_out, int out_size, void* d_ws, size_t ws_size,
                              hipStream_t stream) {
  (void)in_sizes; (void)n_in; (void)out_size; (void)ws_size;
  const int*   X    = (const int*)d_in[0];
  const float* glo  = (const float*)d_in[1];
  const float* loch = (const float*)d_in[2];
  const float* loco = (const float*)d_in[3];
  const float* emb  = (const float*)d_in[4];
  const float* W_ih = (const float*)d_in[5];
  const float* W_hh = (const float*)d_in[6];
  const float* b_ih = (const float*)d_in[7];
  const float* b_hh = (const float*)d_in[8];
  const float* Wg   = (const float*)d_in[9];
  const float* Wl   = (const float*)d_in[10];
  const float* Wv_w = (const float*)d_in[11];
  const float* Wv_b = (const float*)d_in[12];
  const float* wh   = (const float*)d_in[13];
  const float* wc   = (const float*)d_in[14];
  const float* wy   = (const float*)d_in[15];
  const float* fc_w = (const float*)d_in[16];
  const float* fc_b = (const float*)d_in[17];

  float* ws   = (float*)d_ws;
  float* Y    = ws + OFF_Y;
  float* GX   = ws + OFF_GX;
  float* OUT  = ws + OFF_OUT;
  unsigned long long* HBUF = (unsigned long long*)(ws + OFF_HBUF);
  int*   CLAIM = (int*)(ws + OFF_CLAIM);
  float* MG   = ws + OFF_MG;
  float* ML   = ws + OFF_ML;
  float* C    = ws + OFF_C;
  float* CG   = ws + OFF_CG;
  float* BETA = ws + OFF_BETA;
  float* PGEN = ws + OFF_PGEN;
  float* OP   = ws + OFF_OP;
  float* MP   = ws + OFF_MP;
  float* LP   = ws + OFF_LP;

  hipMemsetAsync(HBUF, 0, 2*HH*sizeof(unsigned long long), stream);
  hipMemsetAsync(CLAIM, 0, 2*sizeof(int), stream);
  k_embed_gx<<<TT, 256, 0, stream>>>(X, emb, W_ih, b_ih, Y, GX);
  k_gru<<<GRID_GRU, 256, 0, stream>>>(GX, W_hh, b_hh, glo, loch, OUT, HBUF, CLAIM, GRID_GRU);
  k_proj<<<TT, 256, 0, stream>>>(OUT, Y, Wg, Wl, wh, wy, MG, ML, PGEN);
  k_local<<<TT, 128, 0, stream>>>(ML, loco, wc, PGEN, C, BETA, PGEN);
  k_flash<<<QT*NSPL*2, 256, 0, stream>>>(MG, glo, OP, MP, LP);
  k_combine<<<TT, 64, 0, stream>>>(OP, MP, LP, CG);
  k_final<<<TT, 256, 0, stream>>>(OUT, C, CG, BETA, PGEN, Wv_w, Wv_b, fc_w, fc_b, (float*)d_out);
}

// Round 7
// 5580.841 us; speedup vs baseline: 2.3444x; 1.7642x over previous
//
#include <hip/hip_runtime.h>
#include <math.h>

#define TT 2048
#define NKEYS 50000
#define EE 128
#define HH 512
#define H3 1536
#define DH 256
#define VOCAB 1704
#define NLOC 100

#define GB 32      // GRU worker blocks
#define GC 16      // h-elements per GRU worker
#define GRID_GRU 256
#define GXC 64     // gx prefetch chunk (steps)

#define NSPL 8     // flash N-splits
#define SLICE 6256 // per-split keys (multiple of 16 -> aligned b128); last split 6208
#define GTS 50048  // Gt row stride (keys, padded)

using bf16x8 = __attribute__((ext_vector_type(8))) short;
using f32x4  = __attribute__((ext_vector_type(4))) float;

static __device__ __forceinline__ unsigned short f2bf(float f){
  union { float f; unsigned u; } v; v.f = f;
  unsigned r = (v.u + 0x7FFFu + ((v.u >> 16) & 1u)) >> 16;
  return (unsigned short)r;
}

// ---- workspace layout (float offsets) ----
static constexpr size_t OFF_Y     = 0;                                   // 262144
static constexpr size_t OFF_GX    = OFF_Y    + (size_t)TT*EE;            // 3145728
static constexpr size_t OFF_OUT   = OFF_GX   + (size_t)TT*H3;            // 1048576
static constexpr size_t OFF_HBUF  = OFF_OUT  + (size_t)TT*HH;            // 2048 (1024 u64)
static constexpr size_t OFF_CLAIM = OFF_HBUF + 4*HH;                     // 8
static constexpr size_t OFF_MGH   = OFF_CLAIM + 8;                       // 2048*256 bf16 = 262144 f
static constexpr size_t OFF_ML    = OFF_MGH  + (size_t)TT*DH/2;
static constexpr size_t OFF_C     = OFF_ML   + (size_t)TT*DH;
static constexpr size_t OFF_CG    = OFF_C    + (size_t)TT*DH;
static constexpr size_t OFF_BETA  = OFF_CG   + (size_t)TT*DH;
static constexpr size_t OFF_PGEN  = OFF_BETA + (size_t)TT*NLOC;
static constexpr size_t OFF_OP    = OFF_PGEN + TT;                       // 8*2048*256
static constexpr size_t OFF_MP    = OFF_OP   + (size_t)NSPL*TT*DH;
static constexpr size_t OFF_LP    = OFF_MP   + (size_t)NSPL*TT;
static constexpr size_t OFF_GH    = OFF_LP   + (size_t)NSPL*TT;          // 50000*256 bf16
static constexpr size_t OFF_GT    = OFF_GH   + (size_t)NKEYS*DH/2;       // 256*50048 bf16

// ---------------- embedding + gx = y@W_ih^T + b_ih ----------------
__global__ void k_embed_gx(const int* __restrict__ X, const float* __restrict__ emb,
                           const float* __restrict__ W_ih, const float* __restrict__ b_ih,
                           float* __restrict__ Y, float* __restrict__ GX){
  int t = blockIdx.x, tid = threadIdx.x;
  __shared__ float yr[EE];
  int xid = X[t];
  if (tid < EE){ float v = emb[(size_t)xid*EE + tid]; yr[tid] = v; Y[(size_t)t*EE + tid] = v; }
  __syncthreads();
  for (int i=0;i<6;i++){
    int r = tid + 256*i;
    const float4* w = (const float4*)(W_ih + (size_t)r*EE);
    float acc = b_ih[r];
    #pragma unroll
    for (int k4=0;k4<EE/4;k4++){
      float4 wv = w[k4];
      acc += wv.x*yr[k4*4] + wv.y*yr[k4*4+1] + wv.z*yr[k4*4+2] + wv.w*yr[k4*4+3];
    }
    GX[(size_t)t*H3 + r] = acc;
  }
}

// ---------------- bf16 conversion + 64x256 tiled transpose of G ----------------
__global__ void k_cvt(const float* __restrict__ G, unsigned short* __restrict__ Gh,
                      unsigned short* __restrict__ Gt){
  __shared__ unsigned short tile[64][258];
  int k0 = blockIdx.x*64, tid = threadIdx.x;
  #pragma unroll
  for (int i=0;i<16;i++){
    int idx = tid + 256*i;           // 0..4095
    int r = idx >> 6, c4 = idx & 63; // row 0..63, float4 col 0..63
    int row = k0 + r;
    float4 v = (row < NKEYS) ? ((const float4*)(G + (size_t)row*DH))[c4] : make_float4(0.f,0.f,0.f,0.f);
    unsigned short u0=f2bf(v.x), u1=f2bf(v.y), u2=f2bf(v.z), u3=f2bf(v.w);
    tile[r][c4*4+0]=u0; tile[r][c4*4+1]=u1; tile[r][c4*4+2]=u2; tile[r][c4*4+3]=u3;
    if (row < NKEYS){
      ushort4 u4; u4.x=u0; u4.y=u1; u4.z=u2; u4.w=u3;
      ((ushort4*)(Gh + (size_t)row*DH))[c4] = u4;
    }
  }
  __syncthreads();
  int d = tid;  // 0..255
  unsigned short vals[64];
  #pragma unroll
  for (int k=0;k<64;k++) vals[k] = tile[k][d];
  #pragma unroll
  for (int g2=0; g2<8; g2++){
    uint4 w;
    w.x = (unsigned)vals[g2*8+0] | ((unsigned)vals[g2*8+1]<<16);
    w.y = (unsigned)vals[g2*8+2] | ((unsigned)vals[g2*8+3]<<16);
    w.z = (unsigned)vals[g2*8+4] | ((unsigned)vals[g2*8+5]<<16);
    w.w = (unsigned)vals[g2*8+6] | ((unsigned)vals[g2*8+7]<<16);
    ((uint4*)(Gt + (size_t)d*GTS + k0))[g2] = w;
  }
}

// ---------------- GRU scan: register-resident W_hh, wave-local gates (unchanged R6) ----------------
__global__ __launch_bounds__(256, 1) void k_gru(const float* __restrict__ GX, const float* __restrict__ W_hh,
          const float* __restrict__ b_hh, const float* __restrict__ glo, const float* __restrict__ loch,
          float* __restrict__ out, unsigned long long* hbuf, int* claim, int nblocks){
  __shared__ float gxl[GXC*48];
  __shared__ float outbuf[GXC*GC];
  __shared__ float hl[512];
  __shared__ float ghw[4][12];
  __shared__ float pbuf[4][12][65];
  __shared__ int widx_sh;
  int tid = threadIdx.x;

  if (tid==0){
    unsigned xcc;
    asm volatile("s_getreg_b32 %0, hwreg(HW_REG_XCC_ID, 0, 32)" : "=s"(xcc));
    int my = -1;
    if (xcc == 0u) my = atomicAdd(&claim[0], 1);
    __hip_atomic_fetch_add(&claim[1], 1, __ATOMIC_RELAXED, __HIP_MEMORY_SCOPE_AGENT);
    if (my < 0){
      for(;;){
        int c = __hip_atomic_load(&claim[0], __ATOMIC_RELAXED, __HIP_MEMORY_SCOPE_AGENT);
        if (c >= GB) break;
        int a = __hip_atomic_load(&claim[1], __ATOMIC_RELAXED, __HIP_MEMORY_SCOPE_AGENT);
        if (a >= nblocks){ my = atomicAdd(&claim[0], 1); break; }
      }
    }
    widx_sh = my;
  }
  __syncthreads();
  int b = widx_sh;
  if (b < 0 || b >= GB) return;

  int i0 = b*GC;
  int wave = tid>>6, lane = tid&63;

  float wreg[12][8];
  #pragma unroll
  for (int c=0;c<3;c++){
    #pragma unroll
    for (int j=0;j<4;j++){
      const float* wr = W_hh + (size_t)(c*512 + i0 + 4*wave + j)*512;
      #pragma unroll
      for (int m=0;m<8;m++) wreg[c*4+j][m] = wr[lane + 64*m];
    }
  }
  hl[tid]     = glo[tid];
  hl[tid+256] = loch[tid];
  float bhr=0.f,bhz=0.f,bhn=0.f,hprev=0.f;
  int e = 4*wave + lane;
  if (lane < 4){
    bhr = b_hh[i0+e]; bhz = b_hh[512+i0+e]; bhn = b_hh[1024+i0+e];
    int hi = i0 + e;
    hprev = (hi < 256) ? glo[hi] : loch[hi-256];
  }
  __syncthreads();
  int r4 = lane>>2, q4 = lane&3;
  for (int t=0;t<TT;t++){
    int s = t & (GXC-1);
    if (s == 0){
      if (t > 0){
        int t0 = t - GXC;
        float4 ov = ((float4*)outbuf)[tid];
        int s2 = tid >> 2, c4 = tid & 3;
        *(float4*)&out[(size_t)(t0+s2)*HH + i0 + c4*4] = ov;
      }
      #pragma unroll
      for (int k=0;k<3;k++){
        int idx = tid + 256*k;
        int sp = idx / 12, q = idx % 12;
        int g = q >> 2, c4 = q & 3;
        ((float4*)gxl)[idx] = ((const float4*)(GX + (size_t)(t+sp)*H3 + g*512 + i0))[c4];
      }
      __syncthreads();
    }
    float hreg[8];
    #pragma unroll
    for (int m=0;m<8;m++) hreg[m] = hl[lane + 64*m];
    float p[12];
    #pragma unroll
    for (int rr=0;rr<12;rr++){
      float acc = 0.f;
      #pragma unroll
      for (int m=0;m<8;m++) acc = fmaf(wreg[rr][m], hreg[m], acc);
      p[rr] = acc;
    }
    #pragma unroll
    for (int rr=0;rr<12;rr++) pbuf[wave][rr][lane] = p[rr];
    __builtin_amdgcn_wave_barrier();
    if (r4 < 12){
      const float* pb = &pbuf[wave][r4][q4*16];
      float sum = 0.f;
      #pragma unroll
      for (int j=0;j<16;j++) sum += pb[j];
      sum += __shfl_xor(sum, 1, 64);
      sum += __shfl_xor(sum, 2, 64);
      if (q4 == 0) ghw[wave][r4] = sum;
    }
    __builtin_amdgcn_wave_barrier();
    int slot = (t+1)&1;
    if (lane < 4){
      float ghr = ghw[wave][lane];
      float ghz = ghw[wave][4+lane];
      float ghn = ghw[wave][8+lane];
      float gxr = gxl[s*48 + e];
      float gxz = gxl[s*48 + 16 + e];
      float gxn = gxl[s*48 + 32 + e];
      float rg = 1.f/(1.f + __expf(-(gxr + ghr + bhr)));
      float zg = 1.f/(1.f + __expf(-(gxz + ghz + bhz)));
      float nx = gxn + bhn + rg*ghn;
      float ex = __expf(-2.f*fabsf(nx));
      float tt2 = (1.f-ex)/(1.f+ex);
      float ng = (nx >= 0.f) ? tt2 : -tt2;
      float hn = (1.f - zg)*ng + zg*hprev;
      outbuf[s*GC + e] = hn;
      unsigned long long pk = ((unsigned long long)(unsigned)(t+1) << 32) | (unsigned long long)__float_as_uint(hn);
      __hip_atomic_store(&hbuf[slot*HH + i0 + e], pk, __ATOMIC_RELAXED, __HIP_MEMORY_SCOPE_AGENT);
      hprev = hn;
    }
    if (t+1 < TT){
      unsigned want = (unsigned)(t+1);
      const unsigned long long* hb = &hbuf[slot*HH];
      unsigned long long v0=0ull, v1=0ull;
      bool f0=false, f1=false;
      for(;;){
        if (!f0){ v0 = __hip_atomic_load(&hb[tid],     __ATOMIC_RELAXED, __HIP_MEMORY_SCOPE_AGENT); f0 = ((unsigned)(v0>>32) == want); }
        if (!f1){ v1 = __hip_atomic_load(&hb[tid+256], __ATOMIC_RELAXED, __HIP_MEMORY_SCOPE_AGENT); f1 = ((unsigned)(v1>>32) == want); }
        if (f0 && f1) break;
        __builtin_amdgcn_s_sleep(1);
      }
      hl[tid]     = __uint_as_float((unsigned)v0);
      hl[tid+256] = __uint_as_float((unsigned)v1);
      __syncthreads();
    }
  }
  __syncthreads();
  {
    int t0 = TT - GXC;
    float4 ov = ((float4*)outbuf)[tid];
    int s2 = tid >> 2, c4 = tid & 3;
    *(float4*)&out[(size_t)(t0+s2)*HH + i0 + c4*4] = ov;
  }
}

// ---------------- M_g (bf16), M_l = out@W_ga_*, pgen base ----------------
__global__ void k_proj(const float* __restrict__ out, const float* __restrict__ Y,
                       const float* __restrict__ Wg, const float* __restrict__ Wl,
                       const float* __restrict__ wh, const float* __restrict__ wy,
                       unsigned short* __restrict__ MGh, float* __restrict__ ML, float* __restrict__ PGB){
  int t = blockIdx.x, tid = threadIdx.x;
  __shared__ float orow[512];
  __shared__ float red[256];
  orow[tid]     = out[(size_t)t*HH + tid];
  orow[tid+256] = out[(size_t)t*HH + tid+256];
  __syncthreads();
  float mg=0.f, ml=0.f;
  for (int h=0; h<HH; h++){
    float ov = orow[h];
    mg = fmaf(ov, Wg[(size_t)h*DH + tid], mg);
    ml = fmaf(ov, Wl[(size_t)h*DH + tid], ml);
  }
  MGh[(size_t)t*DH + tid] = f2bf(mg);
  ML[(size_t)t*DH + tid] = ml;
  float pr = orow[tid]*wh[tid] + orow[tid+256]*wh[tid+256];
  if (tid < EE) pr += Y[(size_t)t*EE + tid]*wy[tid];
  red[tid] = pr;
  __syncthreads();
  for (int s=128; s>0; s>>=1){ if (tid < s) red[tid] += red[tid+s]; __syncthreads(); }
  if (tid==0) PGB[t] = red[0];
}

// ---------------- local attention + p_gen ----------------
__global__ void k_local(const float* __restrict__ ML, const float* __restrict__ locout,
                        const float* __restrict__ wc, const float* __restrict__ PGB,
                        float* __restrict__ C, float* __restrict__ BETA, float* __restrict__ PGEN){
  int t = blockIdx.x, tid = threadIdx.x; // 128 threads
  __shared__ float mlr[DH];
  __shared__ float sl[NLOC];
  __shared__ float crow[DH];
  __shared__ float red[128];
  __shared__ float mx; __shared__ float inv;
  mlr[tid]     = ML[(size_t)t*DH + tid];
  mlr[tid+128] = ML[(size_t)t*DH + tid+128];
  __syncthreads();
  if (tid < NLOC){
    const float* gl = locout + (size_t)tid*8*DH;
    float s=0.f;
    for (int e=0;e<DH;e++) s = fmaf(gl[e], mlr[e], s);
    sl[tid] = s;
  }
  __syncthreads();
  if (tid==0){ float m = sl[0]; for (int j=1;j<NLOC;j++) m = fmaxf(m, sl[j]); mx = m; }
  __syncthreads();
  if (tid < NLOC) sl[tid] = __expf(sl[tid]-mx);
  __syncthreads();
  if (tid==0){ float su=0.f; for (int j=0;j<NLOC;j++) su += sl[j]; inv = 1.f/su; }
  __syncthreads();
  if (tid < NLOC){ sl[tid] *= inv; BETA[(size_t)t*NLOC + tid] = sl[tid]; }
  __syncthreads();
  {
    float c0=0.f, c1=0.f;
    for (int j=0;j<NLOC;j++){
      float ga = sl[j];
      c0 = fmaf(ga, locout[(size_t)j*8*DH + tid],     c0);
      c1 = fmaf(ga, locout[(size_t)j*8*DH + tid+128], c1);
    }
    C[(size_t)t*DH + tid]     = c0;
    C[(size_t)t*DH + tid+128] = c1;
    crow[tid] = c0; crow[tid+128] = c1;
  }
  __syncthreads();
  red[tid] = crow[tid]*wc[tid] + crow[tid+128]*wc[tid+128];
  __syncthreads();
  for (int s=64;s>0;s>>=1){ if (tid<s) red[tid]+=red[tid+s]; __syncthreads(); }
  if (tid==0){
    float x = PGB[t] + red[0];
    PGEN[t] = (x > 0.f) ? x : 0.2f*x;
  }
}

// ---------------- MFMA bf16 flash attention over G (K=V), 8-way N split ----------------
// Per block: 64 queries (wave w -> q rows q0+16w..+15), 256 threads.
// S^T = mfma(K_frag, Q^T_frag): D col = lane&15 = q  -> per-lane online softmax
// (reduce over k via shfl_xor 16,32). P^T round-trips 1KB/wave through LDS.
// O^T = mfma(V^T_frag, P^T_frag): D col = q matches -> alpha is scalar per lane.
__global__ __launch_bounds__(256, 1) void k_flash(const unsigned short* __restrict__ MGh,
        const unsigned short* __restrict__ Gh, const unsigned short* __restrict__ Gt,
        float* __restrict__ OP, float* __restrict__ MP, float* __restrict__ LP){
  __shared__ unsigned short P_lds[4][32][16];
  int bid = blockIdx.x;
  int qb = bid & 31, sl = bid >> 5;
  int q0 = qb*64;
  int tid = threadIdx.x;
  int w = tid >> 6, lane = tid & 63;
  int l15 = lane & 15, g = lane >> 4;
  int qrow = q0 + w*16 + l15;

  bf16x8 qf[8];
  #pragma unroll
  for (int f=0; f<8; f++)
    qf[f] = *(const bf16x8*)(MGh + (size_t)qrow*DH + f*32 + g*8);

  f32x4 acc[16];
  #pragma unroll
  for (int c=0;c<16;c++) acc[c] = (f32x4){0.f,0.f,0.f,0.f};
  float m = -1e30f, l = 0.f;

  int k0base = sl*SLICE;
  int kend = (NKEYS - k0base < SLICE) ? (NKEYS - k0base) : SLICE;

  for (int k0=0; k0<kend; k0+=32){
    f32x4 s0 = (f32x4){0.f,0.f,0.f,0.f}, s1 = (f32x4){0.f,0.f,0.f,0.f};
    const unsigned short* arow0 = Gh + (size_t)(k0base + k0 + l15)*DH;
    const unsigned short* arow1 = arow0 + (size_t)16*DH;
    #pragma unroll
    for (int f=0; f<8; f++){
      bf16x8 a0 = *(const bf16x8*)(arow0 + f*32 + g*8);
      bf16x8 a1 = *(const bf16x8*)(arow1 + f*32 + g*8);
      s0 = __builtin_amdgcn_mfma_f32_16x16x32_bf16(a0, qf[f], s0, 0,0,0);
      s1 = __builtin_amdgcn_mfma_f32_16x16x32_bf16(a1, qf[f], s1, 0,0,0);
    }
    int kt = kend - k0;  // >=32 except tail
    #pragma unroll
    for (int r=0;r<4;r++){
      if (4*g + r >= kt)      s0[r] = -1e30f;
      if (16 + 4*g + r >= kt) s1[r] = -1e30f;
    }
    float mx = s0[0];
    #pragma unroll
    for (int r=1;r<4;r++) mx = fmaxf(mx, s0[r]);
    #pragma unroll
    for (int r=0;r<4;r++) mx = fmaxf(mx, s1[r]);
    mx = fmaxf(mx, __shfl_xor(mx, 16, 64));
    mx = fmaxf(mx, __shfl_xor(mx, 32, 64));
    float mnew = fmaxf(m, mx);
    float alpha = __expf(m - mnew);
    float p0[4], p1[4]; float ls = 0.f;
    #pragma unroll
    for (int r=0;r<4;r++){
      p0[r] = __expf(s0[r] - mnew);
      p1[r] = __expf(s1[r] - mnew);
      ls += p0[r] + p1[r];
    }
    ls += __shfl_xor(ls, 16, 64);
    ls += __shfl_xor(ls, 32, 64);
    l = l*alpha + ls;
    m = mnew;
    #pragma unroll
    for (int r=0;r<4;r++){
      P_lds[w][4*g+r][l15]      = f2bf(p0[r]);
      P_lds[w][16+4*g+r][l15]   = f2bf(p1[r]);
    }
    __builtin_amdgcn_wave_barrier();
    bf16x8 pf;
    #pragma unroll
    for (int j=0;j<8;j++) pf[j] = (short)P_lds[w][8*g+j][l15];
    __builtin_amdgcn_wave_barrier();
    const unsigned short* gtb = Gt + (size_t)(k0base + k0 + 8*g);
    #pragma unroll
    for (int c=0;c<16;c++){
      acc[c][0]*=alpha; acc[c][1]*=alpha; acc[c][2]*=alpha; acc[c][3]*=alpha;
      bf16x8 vf = *(const bf16x8*)(gtb + (size_t)(c*16 + l15)*GTS);
      acc[c] = __builtin_amdgcn_mfma_f32_16x16x32_bf16(vf, pf, acc[c], 0,0,0);
    }
  }
  size_t obase = ((size_t)sl*TT + qrow)*DH;
  #pragma unroll
  for (int c=0;c<16;c++){
    float4 v = make_float4(acc[c][0], acc[c][1], acc[c][2], acc[c][3]);
    *(float4*)&OP[obase + c*16 + 4*g] = v;
  }
  if (g == 0){ MP[(size_t)sl*TT + qrow] = m; LP[(size_t)sl*TT + qrow] = l; }
}

// ---------------- combine flash splits ----------------
__global__ void k_combine(const float* __restrict__ OP, const float* __restrict__ MP,
                          const float* __restrict__ LP, float* __restrict__ CG){
  int q = blockIdx.x, tid = threadIdx.x; // 64 threads
  float M = -1e30f;
  float ms[NSPL];
  #pragma unroll
  for (int s=0;s<NSPL;s++){ ms[s] = MP[(size_t)s*TT + q]; M = fmaxf(M, ms[s]); }
  float wgt[NSPL]; float denom = 0.f;
  #pragma unroll
  for (int s=0;s<NSPL;s++){ wgt[s] = __expf(ms[s]-M); denom += LP[(size_t)s*TT + q]*wgt[s]; }
  float inv = 1.f/denom;
  for (int d = tid; d < DH; d += 64){
    float v = 0.f;
    #pragma unroll
    for (int s=0;s<NSPL;s++) v += OP[((size_t)s*TT+q)*DH + d]*wgt[s];
    CG[(size_t)q*DH + d] = v*inv;
  }
}

// ---------------- P_vocab softmax, mixture, final projection ----------------
__global__ void k_final(const float* __restrict__ out, const float* __restrict__ C,
        const float* __restrict__ CG, const float* __restrict__ BETA, const float* __restrict__ PGEN,
        const float* __restrict__ Wv_w, const float* __restrict__ Wv_b,
        const float* __restrict__ fc_w, const float* __restrict__ fc_b, float* __restrict__ O){
  int t = blockIdx.x, tid = threadIdx.x;
  __shared__ float cat[1024];
  __shared__ float pw[NLOC];
  __shared__ float mx; __shared__ float inv;
  cat[tid]     = out[(size_t)t*HH + tid];
  cat[tid+256] = out[(size_t)t*HH + tid+256];
  cat[512+tid] = C[(size_t)t*DH + tid];
  cat[768+tid] = CG[(size_t)t*DH + tid];
  __syncthreads();
  if (tid < NLOC){
    const float4* w = (const float4*)(Wv_w + (size_t)tid*1024);
    float acc = Wv_b[tid];
    for (int i4=0;i4<256;i4++){
      float4 wv = w[i4];
      acc += wv.x*cat[i4*4] + wv.y*cat[i4*4+1] + wv.z*cat[i4*4+2] + wv.w*cat[i4*4+3];
    }
    pw[tid] = acc;
  }
  __syncthreads();
  if (tid==0){ float m=pw[0]; for (int j=1;j<NLOC;j++) m=fmaxf(m,pw[j]); mx=m; }
  __syncthreads();
  if (tid<NLOC) pw[tid] = __expf(pw[tid]-mx);
  __syncthreads();
  if (tid==0){ float s=0.f; for(int j=0;j<NLOC;j++) s+=pw[j]; inv=1.f/s; }
  __syncthreads();
  float pg = PGEN[t];
  if (tid<NLOC) pw[tid] = pg*pw[tid]*inv + (1.f-pg)*BETA[(size_t)t*NLOC+tid];
  __syncthreads();
  for (int o_=tid; o_<VOCAB; o_+=256){
    const float4* fw = (const float4*)(fc_w + (size_t)o_*NLOC);
    float acc = fc_b[o_];
    #pragma unroll
    for (int p4=0;p4<25;p4++){
      float4 wv = fw[p4];
      acc += wv.x*pw[p4*4] + wv.y*pw[p4*4+1] + wv.z*pw[p4*4+2] + wv.w*pw[p4*4+3];
    }
    O[(size_t)t*VOCAB + o_] = acc;
  }
}

extern "C" void kernel_launch(void* const* d_in, const int* in_sizes, int n_in,
                              void* d_out, int out_size, void* d_ws, size_t ws_size,
                              hipStream_t stream) {
  (void)in_sizes; (void)n_in; (void)out_size; (void)ws_size;
  const int*   X    = (const int*)d_in[0];
  const float* glo  = (const float*)d_in[1];
  const float* loch = (const float*)d_in[2];
  const float* loco = (const float*)d_in[3];
  const float* emb  = (const float*)d_in[4];
  const float* W_ih = (const float*)d_in[5];
  const float* W_hh = (const float*)d_in[6];
  const float* b_ih = (const float*)d_in[7];
  const float* b_hh = (const float*)d_in[8];
  const float* Wg   = (const float*)d_in[9];
  const float* Wl   = (const float*)d_in[10];
  const float* Wv_w = (const float*)d_in[11];
  const float* Wv_b = (const float*)d_in[12];
  const float* wh   = (const float*)d_in[13];
  const float* wc   = (const float*)d_in[14];
  const float* wy   = (const float*)d_in[15];
  const float* fc_w = (const float*)d_in[16];
  const float* fc_b = (const float*)d_in[17];

  float* ws   = (float*)d_ws;
  float* Y    = ws + OFF_Y;
  float* GX   = ws + OFF_GX;
  float* OUT  = ws + OFF_OUT;
  unsigned long long* HBUF = (unsigned long long*)(ws + OFF_HBUF);
  int*   CLAIM = (int*)(ws + OFF_CLAIM);
  unsigned short* MGH = (unsigned short*)(ws + OFF_MGH);
  float* ML   = ws + OFF_ML;
  float* C    = ws + OFF_C;
  float* CG   = ws + OFF_CG;
  float* BETA = ws + OFF_BETA;
  float* PGEN = ws + OFF_PGEN;
  float* OP   = ws + OFF_OP;
  float* MP   = ws + OFF_MP;
  float* LP   = ws + OFF_LP;
  unsigned short* GH = (unsigned short*)(ws + OFF_GH);
  unsigned short* GT = (unsigned short*)(ws + OFF_GT);

  hipMemsetAsync(HBUF, 0, 2*HH*sizeof(unsigned long long), stream);
  hipMemsetAsync(CLAIM, 0, 2*sizeof(int), stream);
  k_embed_gx<<<TT, 256, 0, stream>>>(X, emb, W_ih, b_ih, Y, GX);
  k_cvt<<<(NKEYS+63)/64, 256, 0, stream>>>(glo, GH, GT);
  k_gru<<<GRID_GRU, 256, 0, stream>>>(GX, W_hh, b_hh, glo, loch, OUT, HBUF, CLAIM, GRID_GRU);
  k_proj<<<TT, 256, 0, stream>>>(OUT, Y, Wg, Wl, wh, wy, MGH, ML, PGEN);
  k_local<<<TT, 128, 0, stream>>>(ML, loco, wc, PGEN, C, BETA, PGEN);
  k_flash<<<32*NSPL, 256, 0, stream>>>(MGH, GH, GT, OP, MP, LP);
  k_combine<<<TT, 64, 0, stream>>>(OP, MP, LP, CG);
  k_final<<<TT, 256, 0, stream>>>(OUT, C, CG, BETA, PGEN, Wv_w, Wv_b, fc_w, fc_b, (float*)d_out);
}